// Round 5
// baseline (745.365 us; speedup 1.0000x reference)
//
#include <hip/hip_runtime.h>
#include <hip/hip_bf16.h>
#include <hip/hip_fp16.h>

// SwinV2 window attention, MI355X/gfx950.
// Pipeline: cvt_w, cpb, rpb (1MB natural-layout bias, log2e-folded),
//           2x [cvt_x(half) -> attn(half)], proj.
// attn: 1024 thr / 16 waves, wave = 16 q-rows. Phase B uses SWAPPED QK^T
// (D cols = q) so each lane owns one q-row. R5 change: lq folded into the
// dead half of the x double-buffer (lx[1]) -> LDS 94208->77824 B -> 2
// blocks/CU; __launch_bounds__(1024,8) holds VGPR at 64 (512/8).

#define LOG100F 4.605170185988091f
#define LOG2EF 1.4426950408889634f

typedef __attribute__((ext_vector_type(8))) __bf16 bf16x8;
typedef __attribute__((ext_vector_type(4))) float f32x4;
typedef __attribute__((ext_vector_type(8))) unsigned short u16x8;
typedef __attribute__((ext_vector_type(4))) unsigned short u16x4;

__device__ __forceinline__ unsigned short f2bfu(float f) {
  __hip_bfloat16 b = __float2bfloat16(f);
  return __builtin_bit_cast(unsigned short, b);
}
__device__ __forceinline__ unsigned short f2h(float f) {
  __half hv = __float2half(f);
  return __builtin_bit_cast(unsigned short, hv);
}
__device__ __forceinline__ float h2f(unsigned short b) {
  return __half2float(__builtin_bit_cast(__half, b));
}
__device__ __forceinline__ bf16x8 lds8(const unsigned short* p) {
  u16x8 v = *(const u16x8*)p;
  return __builtin_bit_cast(bf16x8, v);
}
__device__ __forceinline__ f32x4 mfma16(bf16x8 a, bf16x8 b, f32x4 c) {
  return __builtin_amdgcn_mfma_f32_16x16x32_bf16(a, b, c, 0, 0, 0);
}
__device__ __forceinline__ float fexp2(float x) {
#if __has_builtin(__builtin_amdgcn_exp2f)
  return __builtin_amdgcn_exp2f(x);
#else
  return exp2f(x);
#endif
}
// 16B-chunk XOR swizzle for [R][32]-u16 tiles: <=2-way on ds_read_b128
__device__ __forceinline__ int swc(int row, int kchunk) {
  return (kchunk ^ (row & 3) ^ ((row >> 2) & 3)) & 3;
}
__device__ __forceinline__ void gload_lds16(const void* g, void* l) {
  __builtin_amdgcn_global_load_lds(
      (const __attribute__((address_space(1))) void*)g,
      (__attribute__((address_space(3))) void*)l, 16, 0, 0);
}

// ---------------- weights -> bf16 ----------------
__global__ void k_cvt_w(const float* __restrict__ qkv_w, const float* __restrict__ proj_w,
                        unsigned short* __restrict__ wqkv, unsigned short* __restrict__ wproj) {
  const int t = blockIdx.x * 256 + threadIdx.x;
  if (t < 768 * 256) {
    wqkv[t] = f2bfu(qkv_w[t]);
  } else {
    const int t2 = t - 768 * 256;
    wproj[t2] = f2bfu(proj_w[t2]);
  }
}

// ---------------- x -> bf16 (half batch per call) ----------------
__global__ void k_cvt_x(const float* __restrict__ x, unsigned short* __restrict__ xb) {
  const int t = blockIdx.x * 256 + threadIdx.x;
  const float4 a = *(const float4*)(x + (size_t)t * 8);
  const float4 c = *(const float4*)(x + (size_t)t * 8 + 4);
  u16x8 ov;
  ov[0] = f2bfu(a.x); ov[1] = f2bfu(a.y); ov[2] = f2bfu(a.z); ov[3] = f2bfu(a.w);
  ov[4] = f2bfu(c.x); ov[5] = f2bfu(c.y); ov[6] = f2bfu(c.z); ov[7] = f2bfu(c.w);
  *(u16x8*)(xb + (size_t)t * 8) = ov;
}

// ---------------- CPB MLP -> bias_table[961][8] ----------------
__global__ void k_cpb(const float* __restrict__ w1, const float* __restrict__ b1,
                      const float* __restrict__ w2, float* __restrict__ bt) {
  const int row = blockIdx.x;
  const int lane = threadIdx.x;
  const int i = row / 31, j = row % 31;
  float x0 = (i - 15) * (1.0f / 15.0f);
  float x1 = (j - 15) * (1.0f / 15.0f);
  float v0 = log2f(fmaf(8.0f, fabsf(x0), 1.0f)) * (1.0f / 3.0f); v0 = x0 < 0.0f ? -v0 : v0;
  float v1 = log2f(fmaf(8.0f, fabsf(x1), 1.0f)) * (1.0f / 3.0f); v1 = x1 < 0.0f ? -v1 : v1;
  float a[8] = {0.f, 0.f, 0.f, 0.f, 0.f, 0.f, 0.f, 0.f};
  for (int jj = lane; jj < 512; jj += 64) {
    float hv = fmaf(w1[2 * jj], v0, fmaf(w1[2 * jj + 1], v1, b1[jj]));
    hv = fmaxf(hv, 0.0f);
#pragma unroll
    for (int hh = 0; hh < 8; ++hh) a[hh] = fmaf(hv, w2[hh * 512 + jj], a[hh]);
  }
#pragma unroll
  for (int hh = 0; hh < 8; ++hh) {
#pragma unroll
    for (int mm = 1; mm < 64; mm <<= 1) a[hh] += __shfl_xor(a[hh], mm);
  }
  float outv = a[0];
#pragma unroll
  for (int hh = 1; hh < 8; ++hh)
    if (lane == hh) outv = a[hh];
  if (lane < 8) bt[row * 8 + lane] = outv;
}

// ------- rpbn[h][n][m] = fp16(log2e * 16*sigmoid(bt[idx(n,m)][h])) -------
__global__ void k_rpb(const float* __restrict__ bt, unsigned short* __restrict__ rpbn) {
  const int t = blockIdx.x * 256 + threadIdx.x;  // 2048 blocks -> 524288
  const int m = t & 255, n = (t >> 8) & 255, h = t >> 16;
  const int ih = n >> 4, iw = n & 15, jh = m >> 4, jw = m & 15;
  const int idx = (ih - jh + 15) * 31 + (iw - jw + 15);
  const float bv = bt[idx * 8 + h];
  rpbn[t] = f2h(LOG2EF * 16.0f / (1.0f + __expf(-bv)));
}

// ---------------- fused qkv + cosine attention, per (b,h) ----------------
__global__ __launch_bounds__(1024, 8) void k_attn(
    const unsigned short* __restrict__ xb, const float* __restrict__ q_bias,
    const float* __restrict__ v_bias, const float* __restrict__ logit_scale,
    const unsigned short* __restrict__ wqkv, const unsigned short* __restrict__ rpbn,
    const float* __restrict__ mask, unsigned short* __restrict__ Obuf, int b0) {
  // 77,824 B total -> 2 blocks/CU. lx[0] reused as psw in PV; lx[1] as lq.
  __shared__ unsigned short lx[2][8192];  // x slice [256 tok][32 k], dbuf
  __shared__ unsigned short lw[2][3072];  // W_h slice [96][32], dbuf
  __shared__ unsigned short lk[8192];     // k-hat [256 tok][32 d]
  __shared__ unsigned short lv[8192];     // v^T  [32 d][256 tok]
  unsigned short* const lq = &lx[1][0];   // q-hat, alias (valid after phase A)

  // XCD-aware map: bid = g*64 + h*8 + x (x = XCD = bid%8); bl = g*8 + x.
  const int bid = blockIdx.x;
  const int xcd = bid & 7, h = (bid >> 3) & 7, g = bid >> 6;
  const int bl = g * 8 + xcd;
  const int b = b0 + bl;
  const int w = b & 63;
  const int tid = threadIdx.x;
  const int lane = tid & 63, wid = tid >> 6;
  const int l16 = lane & 15, lg = lane >> 4;

  // ---- phase A: [96 wcols x 256 tok] = W_h . x^T, K=256 in 8 slices ----
  const int srow = wid * 16 + (lane >> 2);
  const int pc = lane & 3;
  const int xlc = (pc ^ (srow & 3) ^ ((srow >> 2) & 3)) & 3;
  const unsigned short* xsrc0 = xb + (((bl << 8) + srow) << 8) + (xlc << 3);
  const unsigned short* wsrc0 =
      wqkv + ((((srow >> 5) << 8) + h * 32 + (srow & 31)) << 8) + (xlc << 3);

  f32x4 acc[6];
#pragma unroll
  for (int i = 0; i < 6; ++i) acc[i] = (f32x4){0.f, 0.f, 0.f, 0.f};

  gload_lds16(xsrc0, &lx[0][wid * 512]);
  if (wid < 6) gload_lds16(wsrc0, &lw[0][wid * 512]);
  __syncthreads();

  for (int kt = 0; kt < 8; ++kt) {
    const int cur = kt & 1;
    if (kt < 7) {
      const int k0 = (kt + 1) << 5;
      gload_lds16(xsrc0 + k0, &lx[cur ^ 1][wid * 512]);
      if (wid < 6) gload_lds16(wsrc0 + k0, &lw[cur ^ 1][wid * 512]);
    }
    const unsigned short* lxb = lx[cur];
    const unsigned short* lwb = lw[cur];
    const int n = wid * 16 + l16;
    const bf16x8 ax = lds8(lxb + n * 32 + (swc(n, lg) << 3));
#pragma unroll
    for (int mf = 0; mf < 6; ++mf) {
      const int m = mf * 16 + l16;
      const bf16x8 aw = lds8(lwb + m * 32 + (swc(m, lg) << 3));
      acc[mf] = mfma16(aw, ax, acc[mf]);
    }
    __syncthreads();
  }

  // ---- epilogue: lane owns token tok = wid*16+l16; d = mf*16+lg*4+r ----
  const float sl = __expf(fminf(logit_scale[h], LOG100F)) * LOG2EF;
  const int tok = wid * 16 + l16;
  const float4 qb0 = *(const float4*)(q_bias + h * 32 + lg * 4);
  const float4 qb1 = *(const float4*)(q_bias + h * 32 + 16 + lg * 4);
  const float4 vb0 = *(const float4*)(v_bias + h * 32 + lg * 4);
  const float4 vb1 = *(const float4*)(v_bias + h * 32 + 16 + lg * 4);

  float q0[4], q1[4], k0v[4], k1v[4];
  float sq = 0.f, sk = 0.f;
#pragma unroll
  for (int r = 0; r < 4; ++r) {
    q0[r] = acc[0][r] + ((const float*)&qb0)[r];
    q1[r] = acc[1][r] + ((const float*)&qb1)[r];
    k0v[r] = acc[2][r];
    k1v[r] = acc[3][r];
    sq += q0[r] * q0[r] + q1[r] * q1[r];
    sk += k0v[r] * k0v[r] + k1v[r] * k1v[r];
  }
  sq += __shfl_xor(sq, 16); sq += __shfl_xor(sq, 32);
  sk += __shfl_xor(sk, 16); sk += __shfl_xor(sk, 32);
  const float rq = sl / fmaxf(sqrtf(sq), 1e-12f);
  const float rk = 1.f / fmaxf(sqrtf(sk), 1e-12f);
  {
    const int off0 = (lg & 1) * 4;
    u16x4 a, c;
#pragma unroll
    for (int r = 0; r < 4; ++r) { a[r] = f2bfu(q0[r] * rq); c[r] = f2bfu(k0v[r] * rk); }
    const int kc0 = lg >> 1;
    *(u16x4*)(lq + tok * 32 + (swc(tok, kc0) << 3) + off0) = a;
    *(u16x4*)(lk + tok * 32 + (swc(tok, kc0) << 3) + off0) = c;
    u16x4 a2, c2;
#pragma unroll
    for (int r = 0; r < 4; ++r) { a2[r] = f2bfu(q1[r] * rq); c2[r] = f2bfu(k1v[r] * rk); }
    const int kc1 = 2 + (lg >> 1);
    *(u16x4*)(lq + tok * 32 + (swc(tok, kc1) << 3) + off0) = a2;
    *(u16x4*)(lk + tok * 32 + (swc(tok, kc1) << 3) + off0) = c2;
  }
#pragma unroll
  for (int mf = 0; mf < 2; ++mf) {
    const float4 vb = mf ? vb1 : vb0;
#pragma unroll
    for (int r = 0; r < 4; ++r) {
      const int dd = mf * 16 + lg * 4 + r;
      const float vv = acc[4 + mf][r] + ((const float*)&vb)[r];
      lv[dd * 256 + ((((tok >> 3) ^ dd) & 31) << 3) + (tok & 7)] = f2bfu(vv);
    }
  }
  __syncthreads();

  // ---- phase B (swapped): s[cf] = mfma(k-hat, q-hat) -> lane owns q = l16 ----
  const int q = wid * 16 + l16;
  const bf16x8 aq = lds8(lq + q * 32 + (swc(q, lg) << 3));
  f32x4 s[16];
#pragma unroll
  for (int cf = 0; cf < 16; ++cf) {
    const int m = cf * 16 + l16;
    const bf16x8 bk = lds8(lk + m * 32 + (swc(m, lg) << 3));
    s[cf] = mfma16(bk, aq, (f32x4){0.f, 0.f, 0.f, 0.f});
  }
  // bias: natural layout, row q fixed per lane, m = cf*16+lg*4+r consecutive
  const unsigned short* rbp = rpbn + (h << 16) + (q << 8) + lg * 4;
  const float* mbp = mask + (w << 16) + (q << 8) + lg * 4;
#pragma unroll
  for (int cf = 0; cf < 16; ++cf) {
    const u16x4 rv = *(const u16x4*)(rbp + cf * 16);
    const float4 mv = *(const float4*)(mbp + cf * 16);
    s[cf][0] = fmaf(mv.x, LOG2EF, s[cf][0] + h2f(rv[0]));
    s[cf][1] = fmaf(mv.y, LOG2EF, s[cf][1] + h2f(rv[1]));
    s[cf][2] = fmaf(mv.z, LOG2EF, s[cf][2] + h2f(rv[2]));
    s[cf][3] = fmaf(mv.w, LOG2EF, s[cf][3] + h2f(rv[3]));
  }
  // softmax over m: 64 in-lane values + lg-reduce (xor 16, 32); exp2 domain
  float mx = s[0][0];
#pragma unroll
  for (int cf = 0; cf < 16; ++cf) {
#pragma unroll
    for (int r = 0; r < 4; ++r) mx = fmaxf(mx, s[cf][r]);
  }
  mx = fmaxf(mx, __shfl_xor(mx, 16));
  mx = fmaxf(mx, __shfl_xor(mx, 32));
  float sm = 0.f;
#pragma unroll
  for (int cf = 0; cf < 16; ++cf) {
#pragma unroll
    for (int r = 0; r < 4; ++r) {
      const float p = fexp2(s[cf][r] - mx);
      s[cf][r] = p;
      sm += p;
    }
  }
  sm += __shfl_xor(sm, 16);
  sm += __shfl_xor(sm, 32);
  const float inv = 1.f / sm;  // per-lane: normalizer for q-row l16 (deferred)

  // PV: lane holds P[m][q=l16]; stage into psw rows = q_local = l16 (u16x4)
  f32x4 o0 = (f32x4){0.f, 0.f, 0.f, 0.f}, o1 = (f32x4){0.f, 0.f, 0.f, 0.f};
  unsigned short* psw = &lx[0][0] + wid * 512;
#pragma unroll
  for (int cc = 0; cc < 8; ++cc) {
#pragma unroll
    for (int q8 = 0; q8 < 2; ++q8) {
      const int cf = cc * 2 + q8;
      u16x4 pk;
#pragma unroll
      for (int r = 0; r < 4; ++r) pk[r] = f2bfu(s[cf][r]);
      const int ch = q8 * 2 + (lg >> 1);
      *(u16x4*)(psw + l16 * 32 + (swc(l16, ch) << 3) + (lg & 1) * 4) = pk;
    }
    asm volatile("s_waitcnt lgkmcnt(0)" ::: "memory");
    __builtin_amdgcn_sched_barrier(0);
    const bf16x8 pa = lds8(psw + l16 * 32 + (swc(l16, lg) << 3));
    const int d0 = l16;
    const bf16x8 bv0 = lds8(lv + d0 * 256 + ((((cc * 4 + lg) ^ d0) & 31) << 3));
    o0 = mfma16(pa, bv0, o0);
    const int d1 = 16 + l16;
    const bf16x8 bv1 = lds8(lv + d1 * 256 + ((((cc * 4 + lg) ^ d1) & 31) << 3));
    o1 = mfma16(pa, bv1, o1);
    __builtin_amdgcn_sched_barrier(0);
  }
  // O rows = q_local = lg*4+r; fetch that row's normalizer from lane lg*4+r
#pragma unroll
  for (int r = 0; r < 4; ++r) {
    const float iv = __shfl(inv, lg * 4 + r);
    const int row = (b * 256 + wid * 16 + lg * 4 + r) << 8;
    Obuf[row + h * 32 + l16] = f2bfu(o0[r] * iv);
    Obuf[row + h * 32 + 16 + l16] = f2bfu(o1[r] * iv);
  }
}

// ---------------- out = O @ proj_w^T + proj_b (fp32) ----------------
__global__ __launch_bounds__(256, 2) void k_proj(
    const unsigned short* __restrict__ Obuf, const unsigned short* __restrict__ wproj,
    const float* __restrict__ proj_b, float* __restrict__ out) {
  __shared__ unsigned short la[128 * 32];
  __shared__ unsigned short lb[128 * 32];
  const int rb = blockIdx.x >> 1, cb = blockIdx.x & 1;
  const int tid = threadIdx.x, lane = tid & 63, wid = tid >> 6;
  const int wr = wid >> 1, wc = wid & 1;
  const int l16 = lane & 15, lg = lane >> 4;
  f32x4 acc[4][4];
#pragma unroll
  for (int i = 0; i < 4; ++i)
#pragma unroll
    for (int j = 0; j < 4; ++j) acc[i][j] = (f32x4){0.f, 0.f, 0.f, 0.f};
  for (int kt = 0; kt < 8; ++kt) {
    const int k0 = kt * 32;
#pragma unroll
    for (int it = 0; it < 2; ++it) {
      const int task = it * 256 + tid;
      const int row = task >> 2, c = task & 3;
      u16x8 va = *(const u16x8*)(Obuf + (rb * 128 + row) * 256 + k0 + c * 8);
      *(u16x8*)(la + row * 32 + ((c ^ (row & 3)) << 3)) = va;
      u16x8 vb = *(const u16x8*)(wproj + (cb * 128 + row) * 256 + k0 + c * 8);
      *(u16x8*)(lb + row * 32 + ((c ^ (row & 3)) << 3)) = vb;
    }
    __syncthreads();
    bf16x8 a[4];
#pragma unroll
    for (int af = 0; af < 4; ++af) {
      const int rr = wr * 64 + af * 16 + l16;
      a[af] = lds8(la + rr * 32 + ((lg ^ (rr & 3)) << 3));
    }
#pragma unroll
    for (int cf = 0; cf < 4; ++cf) {
      const int ccc = wc * 64 + cf * 16 + l16;
      bf16x8 bfr = lds8(lb + ccc * 32 + ((lg ^ (ccc & 3)) << 3));
#pragma unroll
      for (int af = 0; af < 4; ++af) acc[af][cf] = mfma16(a[af], bfr, acc[af][cf]);
    }
    __syncthreads();
  }
#pragma unroll
  for (int cf = 0; cf < 4; ++cf) {
    const int col = cb * 128 + wc * 64 + cf * 16 + l16;
    const float pb = proj_b[col];
#pragma unroll
    for (int af = 0; af < 4; ++af)
#pragma unroll
      for (int r = 0; r < 4; ++r) {
        const int row = rb * 128 + wr * 64 + af * 16 + lg * 4 + r;
        out[row * 256 + col] = acc[af][cf][r] + pb;
      }
  }
}

extern "C" void kernel_launch(void* const* d_in, const int* in_sizes, int n_in,
                              void* d_out, int out_size, void* d_ws, size_t ws_size,
                              hipStream_t stream) {
  (void)in_sizes; (void)n_in; (void)out_size; (void)ws_size;
  const float* x = (const float*)d_in[0];
  const float* mask = (const float*)d_in[1];
  const float* qkv_w = (const float*)d_in[2];
  const float* q_bias = (const float*)d_in[3];
  const float* v_bias = (const float*)d_in[4];
  const float* logit_scale = (const float*)d_in[5];
  const float* cpb_w1 = (const float*)d_in[6];
  const float* cpb_b1 = (const float*)d_in[7];
  const float* cpb_w2 = (const float*)d_in[8];
  const float* proj_w = (const float*)d_in[9];
  const float* proj_b = (const float*)d_in[10];
  float* out = (float*)d_out;
  char* ws = (char*)d_ws;

  // workspace layout (~102.3 MB)
  unsigned short* xbb = (unsigned short*)(ws + 0);            // 33,554,432 (half batch)
  unsigned short* Obuf = (unsigned short*)(ws + 33554432);    // 67,108,864
  unsigned short* rpbn = (unsigned short*)(ws + 100663296);   // 1,048,576
  float* bt = (float*)(ws + 101711872);                       // 30,752
  unsigned short* wqkv = (unsigned short*)(ws + 101742624);   // 393,216
  unsigned short* wproj = (unsigned short*)(ws + 102135840);  // 131,072

  k_cvt_w<<<dim3(1024), dim3(256), 0, stream>>>(qkv_w, proj_w, wqkv, wproj);
  k_cpb<<<dim3(961), dim3(64), 0, stream>>>(cpb_w1, cpb_b1, cpb_w2, bt);
  k_rpb<<<dim3(2048), dim3(256), 0, stream>>>(bt, rpbn);

  k_cvt_x<<<dim3(8192), dim3(256), 0, stream>>>(x, xbb);
  k_attn<<<dim3(2048), dim3(1024), 0, stream>>>(xbb, q_bias, v_bias, logit_scale,
                                                wqkv, rpbn, mask, Obuf, 0);
  k_cvt_x<<<dim3(8192), dim3(256), 0, stream>>>(x + 16777216, xbb);
  k_attn<<<dim3(2048), dim3(1024), 0, stream>>>(xbb, q_bias, v_bias, logit_scale,
                                                wqkv, rpbn, mask, Obuf, 256);

  k_proj<<<dim3(2048), dim3(256), 0, stream>>>(Obuf, wproj, proj_b, out);
}

// Round 7
// 414.538 us; speedup vs baseline: 1.7981x; 1.7981x over previous
//
#include <hip/hip_runtime.h>
#include <hip/hip_bf16.h>
#include <hip/hip_fp16.h>

// SwinV2 window attention, MI355X/gfx950.
// Pipeline: cvt_w, cpb, rpb (1MB natural-layout bias, log2e-folded),
//           2x [cvt_x(half) -> attn(half)], proj.
// attn: 1024 thr / 16 waves, 2 blocks/CU (LDS 77824, VGPR<=64 total).
// Phase B: swapped QK^T fused into an ONLINE-SOFTMAX chunk loop (no 64-reg
// S tile -> fits 8-waves/SIMD cap without spills). R7 fix: cross-lg sum of
// the softmax denominator (sm xor-16/32) before inv — R6 dropped it and
// normalized by 1/4 of each row's sum (absmax 331).

#define LOG100F 4.605170185988091f
#define LOG2EF 1.4426950408889634f

typedef __attribute__((ext_vector_type(8))) __bf16 bf16x8;
typedef __attribute__((ext_vector_type(4))) float f32x4;
typedef __attribute__((ext_vector_type(8))) unsigned short u16x8;
typedef __attribute__((ext_vector_type(4))) unsigned short u16x4;

__device__ __forceinline__ unsigned short f2bfu(float f) {
  __hip_bfloat16 b = __float2bfloat16(f);
  return __builtin_bit_cast(unsigned short, b);
}
__device__ __forceinline__ unsigned short f2h(float f) {
  __half hv = __float2half(f);
  return __builtin_bit_cast(unsigned short, hv);
}
__device__ __forceinline__ float h2f(unsigned short b) {
  return __half2float(__builtin_bit_cast(__half, b));
}
__device__ __forceinline__ bf16x8 lds8(const unsigned short* p) {
  u16x8 v = *(const u16x8*)p;
  return __builtin_bit_cast(bf16x8, v);
}
__device__ __forceinline__ f32x4 mfma16(bf16x8 a, bf16x8 b, f32x4 c) {
  return __builtin_amdgcn_mfma_f32_16x16x32_bf16(a, b, c, 0, 0, 0);
}
__device__ __forceinline__ float fexp2(float x) {
#if __has_builtin(__builtin_amdgcn_exp2f)
  return __builtin_amdgcn_exp2f(x);
#else
  return exp2f(x);
#endif
}
// 16B-chunk XOR swizzle for [R][32]-u16 tiles: <=2-way on ds_read_b128
__device__ __forceinline__ int swc(int row, int kchunk) {
  return (kchunk ^ (row & 3) ^ ((row >> 2) & 3)) & 3;
}
__device__ __forceinline__ void gload_lds16(const void* g, void* l) {
  __builtin_amdgcn_global_load_lds(
      (const __attribute__((address_space(1))) void*)g,
      (__attribute__((address_space(3))) void*)l, 16, 0, 0);
}

// ---------------- weights -> bf16 ----------------
__global__ void k_cvt_w(const float* __restrict__ qkv_w, const float* __restrict__ proj_w,
                        unsigned short* __restrict__ wqkv, unsigned short* __restrict__ wproj) {
  const int t = blockIdx.x * 256 + threadIdx.x;
  if (t < 768 * 256) {
    wqkv[t] = f2bfu(qkv_w[t]);
  } else {
    const int t2 = t - 768 * 256;
    wproj[t2] = f2bfu(proj_w[t2]);
  }
}

// ---------------- x -> bf16 (half batch per call) ----------------
__global__ void k_cvt_x(const float* __restrict__ x, unsigned short* __restrict__ xb) {
  const int t = blockIdx.x * 256 + threadIdx.x;
  const float4 a = *(const float4*)(x + (size_t)t * 8);
  const float4 c = *(const float4*)(x + (size_t)t * 8 + 4);
  u16x8 ov;
  ov[0] = f2bfu(a.x); ov[1] = f2bfu(a.y); ov[2] = f2bfu(a.z); ov[3] = f2bfu(a.w);
  ov[4] = f2bfu(c.x); ov[5] = f2bfu(c.y); ov[6] = f2bfu(c.z); ov[7] = f2bfu(c.w);
  *(u16x8*)(xb + (size_t)t * 8) = ov;
}

// ---------------- CPB MLP -> bias_table[961][8] ----------------
__global__ void k_cpb(const float* __restrict__ w1, const float* __restrict__ b1,
                      const float* __restrict__ w2, float* __restrict__ bt) {
  const int row = blockIdx.x;
  const int lane = threadIdx.x;
  const int i = row / 31, j = row % 31;
  float x0 = (i - 15) * (1.0f / 15.0f);
  float x1 = (j - 15) * (1.0f / 15.0f);
  float v0 = log2f(fmaf(8.0f, fabsf(x0), 1.0f)) * (1.0f / 3.0f); v0 = x0 < 0.0f ? -v0 : v0;
  float v1 = log2f(fmaf(8.0f, fabsf(x1), 1.0f)) * (1.0f / 3.0f); v1 = x1 < 0.0f ? -v1 : v1;
  float a[8] = {0.f, 0.f, 0.f, 0.f, 0.f, 0.f, 0.f, 0.f};
  for (int jj = lane; jj < 512; jj += 64) {
    float hv = fmaf(w1[2 * jj], v0, fmaf(w1[2 * jj + 1], v1, b1[jj]));
    hv = fmaxf(hv, 0.0f);
#pragma unroll
    for (int hh = 0; hh < 8; ++hh) a[hh] = fmaf(hv, w2[hh * 512 + jj], a[hh]);
  }
#pragma unroll
  for (int hh = 0; hh < 8; ++hh) {
#pragma unroll
    for (int mm = 1; mm < 64; mm <<= 1) a[hh] += __shfl_xor(a[hh], mm);
  }
  float outv = a[0];
#pragma unroll
  for (int hh = 1; hh < 8; ++hh)
    if (lane == hh) outv = a[hh];
  if (lane < 8) bt[row * 8 + lane] = outv;
}

// ------- rpbn[h][n][m] = fp16(log2e * 16*sigmoid(bt[idx(n,m)][h])) -------
__global__ void k_rpb(const float* __restrict__ bt, unsigned short* __restrict__ rpbn) {
  const int t = blockIdx.x * 256 + threadIdx.x;  // 2048 blocks -> 524288
  const int m = t & 255, n = (t >> 8) & 255, h = t >> 16;
  const int ih = n >> 4, iw = n & 15, jh = m >> 4, jw = m & 15;
  const int idx = (ih - jh + 15) * 31 + (iw - jw + 15);
  const float bv = bt[idx * 8 + h];
  rpbn[t] = f2h(LOG2EF * 16.0f / (1.0f + __expf(-bv)));
}

// ---------------- fused qkv + cosine attention, per (b,h) ----------------
__global__ __launch_bounds__(1024, 8) void k_attn(
    const unsigned short* __restrict__ xb, const float* __restrict__ q_bias,
    const float* __restrict__ v_bias, const float* __restrict__ logit_scale,
    const unsigned short* __restrict__ wqkv, const unsigned short* __restrict__ rpbn,
    const float* __restrict__ mask, unsigned short* __restrict__ Obuf, int b0) {
  // 77,824 B total -> 2 blocks/CU. lx[0] reused as psw in PV; lx[1] as lq.
  __shared__ unsigned short lx[2][8192];  // x slice [256 tok][32 k], dbuf
  __shared__ unsigned short lw[2][3072];  // W_h slice [96][32], dbuf
  __shared__ unsigned short lk[8192];     // k-hat [256 tok][32 d]
  __shared__ unsigned short lv[8192];     // v^T  [32 d][256 tok]
  unsigned short* const lq = &lx[1][0];   // q-hat, alias (valid after phase A)

  // XCD-aware map: bid = g*64 + h*8 + x (x = XCD = bid%8); bl = g*8 + x.
  const int bid = blockIdx.x;
  const int xcd = bid & 7, h = (bid >> 3) & 7, g = bid >> 6;
  const int bl = g * 8 + xcd;
  const int b = b0 + bl;
  const int w = b & 63;
  const int tid = threadIdx.x;
  const int lane = tid & 63, wid = tid >> 6;
  const int l16 = lane & 15, lg = lane >> 4;

  // ---- phase A: [96 wcols x 256 tok] = W_h . x^T, K=256 in 8 slices ----
  const int srow = wid * 16 + (lane >> 2);
  const int pc = lane & 3;
  const int xlc = (pc ^ (srow & 3) ^ ((srow >> 2) & 3)) & 3;
  const unsigned short* xsrc0 = xb + (((bl << 8) + srow) << 8) + (xlc << 3);
  const unsigned short* wsrc0 =
      wqkv + ((((srow >> 5) << 8) + h * 32 + (srow & 31)) << 8) + (xlc << 3);

  f32x4 acc[6];
#pragma unroll
  for (int i = 0; i < 6; ++i) acc[i] = (f32x4){0.f, 0.f, 0.f, 0.f};

  gload_lds16(xsrc0, &lx[0][wid * 512]);
  if (wid < 6) gload_lds16(wsrc0, &lw[0][wid * 512]);
  __syncthreads();

  for (int kt = 0; kt < 8; ++kt) {
    const int cur = kt & 1;
    if (kt < 7) {
      const int k0 = (kt + 1) << 5;
      gload_lds16(xsrc0 + k0, &lx[cur ^ 1][wid * 512]);
      if (wid < 6) gload_lds16(wsrc0 + k0, &lw[cur ^ 1][wid * 512]);
    }
    const unsigned short* lxb = lx[cur];
    const unsigned short* lwb = lw[cur];
    const int n = wid * 16 + l16;
    const bf16x8 ax = lds8(lxb + n * 32 + (swc(n, lg) << 3));
#pragma unroll
    for (int mf = 0; mf < 6; ++mf) {
      const int m = mf * 16 + l16;
      const bf16x8 aw = lds8(lwb + m * 32 + (swc(m, lg) << 3));
      acc[mf] = mfma16(aw, ax, acc[mf]);
    }
    __syncthreads();
  }

  // ---- epilogue: lane owns token tok = wid*16+l16; d = mf*16+lg*4+r ----
  const float sl = __expf(fminf(logit_scale[h], LOG100F)) * LOG2EF;
  const int tok = wid * 16 + l16;
  const float4 qb0 = *(const float4*)(q_bias + h * 32 + lg * 4);
  const float4 qb1 = *(const float4*)(q_bias + h * 32 + 16 + lg * 4);

  {
    float q0[4], q1[4];
    float sq = 0.f, sk = 0.f;
#pragma unroll
    for (int r = 0; r < 4; ++r) {
      q0[r] = acc[0][r] + ((const float*)&qb0)[r];
      q1[r] = acc[1][r] + ((const float*)&qb1)[r];
      sq += q0[r] * q0[r] + q1[r] * q1[r];
      sk += acc[2][r] * acc[2][r] + acc[3][r] * acc[3][r];
    }
    sq += __shfl_xor(sq, 16); sq += __shfl_xor(sq, 32);
    sk += __shfl_xor(sk, 16); sk += __shfl_xor(sk, 32);
    const float rq = sl / fmaxf(sqrtf(sq), 1e-12f);
    const float rk = 1.f / fmaxf(sqrtf(sk), 1e-12f);
    const int off0 = (lg & 1) * 4;
    u16x4 a, c;
#pragma unroll
    for (int r = 0; r < 4; ++r) { a[r] = f2bfu(q0[r] * rq); c[r] = f2bfu(acc[2][r] * rk); }
    const int kc0 = lg >> 1;
    *(u16x4*)(lq + tok * 32 + (swc(tok, kc0) << 3) + off0) = a;
    *(u16x4*)(lk + tok * 32 + (swc(tok, kc0) << 3) + off0) = c;
    u16x4 a2, c2;
#pragma unroll
    for (int r = 0; r < 4; ++r) { a2[r] = f2bfu(q1[r] * rq); c2[r] = f2bfu(acc[3][r] * rk); }
    const int kc1 = 2 + (lg >> 1);
    *(u16x4*)(lq + tok * 32 + (swc(tok, kc1) << 3) + off0) = a2;
    *(u16x4*)(lk + tok * 32 + (swc(tok, kc1) << 3) + off0) = c2;
  }
#pragma unroll
  for (int mf = 0; mf < 2; ++mf) {
    const float4 vb = *(const float4*)(v_bias + h * 32 + mf * 16 + lg * 4);
#pragma unroll
    for (int r = 0; r < 4; ++r) {
      const int dd = mf * 16 + lg * 4 + r;
      const float vv = acc[4 + mf][r] + ((const float*)&vb)[r];
      lv[dd * 256 + ((((tok >> 3) ^ dd) & 31) << 3) + (tok & 7)] = f2bfu(vv);
    }
  }
  __syncthreads();

  // ---- phase B: swapped QK^T + ONLINE softmax + PV, fused chunk loop ----
  // lane owns softmax stats for q-row l16 (partial over its lg's m values);
  // o rows are q_local = lg*4+r.
  const int q = wid * 16 + l16;
  const bf16x8 aq = lds8(lq + q * 32 + (swc(q, lg) << 3));
  const unsigned short* rbp = rpbn + (h << 16) + (q << 8) + lg * 4;
  const float* mbp = mask + (w << 16) + (q << 8) + lg * 4;

  float mx = -3.0e38f, sm = 0.f;
  f32x4 o0 = (f32x4){0.f, 0.f, 0.f, 0.f}, o1 = (f32x4){0.f, 0.f, 0.f, 0.f};
  unsigned short* psw = &lx[0][0] + wid * 512;

  for (int cc = 0; cc < 8; ++cc) {
    // QK^T for this 32-m chunk: s[r] = S[m = cc*32 + (q8*16) + lg*4+r][q=l16]
    const int m0 = cc * 32 + l16;
    const bf16x8 bk0 = lds8(lk + m0 * 32 + (swc(m0, lg) << 3));
    f32x4 s0 = mfma16(bk0, aq, (f32x4){0.f, 0.f, 0.f, 0.f});
    const int m1 = m0 + 16;
    const bf16x8 bk1 = lds8(lk + m1 * 32 + (swc(m1, lg) << 3));
    f32x4 s1 = mfma16(bk1, aq, (f32x4){0.f, 0.f, 0.f, 0.f});
    // bias (natural layout; m = cc*32 + q8*16 + lg*4 + r)
    {
      const u16x4 rv0 = *(const u16x4*)(rbp + cc * 32);
      const float4 mv0 = *(const float4*)(mbp + cc * 32);
      s0[0] = fmaf(mv0.x, LOG2EF, s0[0] + h2f(rv0[0]));
      s0[1] = fmaf(mv0.y, LOG2EF, s0[1] + h2f(rv0[1]));
      s0[2] = fmaf(mv0.z, LOG2EF, s0[2] + h2f(rv0[2]));
      s0[3] = fmaf(mv0.w, LOG2EF, s0[3] + h2f(rv0[3]));
      const u16x4 rv1 = *(const u16x4*)(rbp + cc * 32 + 16);
      const float4 mv1 = *(const float4*)(mbp + cc * 32 + 16);
      s1[0] = fmaf(mv1.x, LOG2EF, s1[0] + h2f(rv1[0]));
      s1[1] = fmaf(mv1.y, LOG2EF, s1[1] + h2f(rv1[1]));
      s1[2] = fmaf(mv1.z, LOG2EF, s1[2] + h2f(rv1[2]));
      s1[3] = fmaf(mv1.w, LOG2EF, s1[3] + h2f(rv1[3]));
    }
    // chunk max over the 32 m (8 in-lane + lg reduce), uniform across lg
    float cmax = fmaxf(fmaxf(fmaxf(s0[0], s0[1]), fmaxf(s0[2], s0[3])),
                       fmaxf(fmaxf(s1[0], s1[1]), fmaxf(s1[2], s1[3])));
    cmax = fmaxf(cmax, __shfl_xor(cmax, 16));
    cmax = fmaxf(cmax, __shfl_xor(cmax, 32));
    const float mnew = fmaxf(mx, cmax);
    const float factor = fexp2(mx - mnew);  // first chunk: exp2(-big)=0
    mx = mnew;
    // p = exp2(s - mnew), accumulate partial sum, pack to bf16, stage
    float lsum = 0.f;
    u16x4 pk0, pk1;
#pragma unroll
    for (int r = 0; r < 4; ++r) {
      const float p = fexp2(s0[r] - mnew);
      lsum += p;
      pk0[r] = f2bfu(p);
    }
#pragma unroll
    for (int r = 0; r < 4; ++r) {
      const float p = fexp2(s1[r] - mnew);
      lsum += p;
      pk1[r] = f2bfu(p);
    }
    sm = sm * factor + lsum;  // per-lane partial (this lg's m only)
    const int ch0 = lg >> 1;
    *(u16x4*)(psw + l16 * 32 + (swc(l16, ch0) << 3) + (lg & 1) * 4) = pk0;
    const int ch1 = 2 + (lg >> 1);
    *(u16x4*)(psw + l16 * 32 + (swc(l16, ch1) << 3) + (lg & 1) * 4) = pk1;
    // rescale o while the staging writes land (o rows = q_local = lg*4+r)
#pragma unroll
    for (int r = 0; r < 4; ++r) {
      const float of = __shfl(factor, lg * 4 + r);
      o0[r] *= of;
      o1[r] *= of;
    }
    asm volatile("s_waitcnt lgkmcnt(0)" ::: "memory");
    __builtin_amdgcn_sched_barrier(0);
    const bf16x8 pa = lds8(psw + l16 * 32 + (swc(l16, lg) << 3));
    const int d0 = l16;
    const bf16x8 bv0 = lds8(lv + d0 * 256 + ((((cc * 4 + lg) ^ d0) & 31) << 3));
    o0 = mfma16(pa, bv0, o0);
    const int d1 = 16 + l16;
    const bf16x8 bv1 = lds8(lv + d1 * 256 + ((((cc * 4 + lg) ^ d1) & 31) << 3));
    o1 = mfma16(pa, bv1, o1);
    __builtin_amdgcn_sched_barrier(0);
  }
  // R7 FIX: total denominator = sum of the 4 lg-group partials (factor
  // history is uniform across lg, so partials add linearly).
  sm += __shfl_xor(sm, 16);
  sm += __shfl_xor(sm, 32);
  // O rows = q_local = lg*4+r; fetch that row's normalizer from lane lg*4+r
  const float inv = 1.f / sm;
#pragma unroll
  for (int r = 0; r < 4; ++r) {
    const float iv = __shfl(inv, lg * 4 + r);
    const int row = (b * 256 + wid * 16 + lg * 4 + r) << 8;
    Obuf[row + h * 32 + l16] = f2bfu(o0[r] * iv);
    Obuf[row + h * 32 + 16 + l16] = f2bfu(o1[r] * iv);
  }
}

// ---------------- out = O @ proj_w^T + proj_b (fp32) ----------------
__global__ __launch_bounds__(256, 2) void k_proj(
    const unsigned short* __restrict__ Obuf, const unsigned short* __restrict__ wproj,
    const float* __restrict__ proj_b, float* __restrict__ out) {
  __shared__ unsigned short la[128 * 32];
  __shared__ unsigned short lb[128 * 32];
  const int rb = blockIdx.x >> 1, cb = blockIdx.x & 1;
  const int tid = threadIdx.x, lane = tid & 63, wid = tid >> 6;
  const int wr = wid >> 1, wc = wid & 1;
  const int l16 = lane & 15, lg = lane >> 4;
  f32x4 acc[4][4];
#pragma unroll
  for (int i = 0; i < 4; ++i)
#pragma unroll
    for (int j = 0; j < 4; ++j) acc[i][j] = (f32x4){0.f, 0.f, 0.f, 0.f};
  for (int kt = 0; kt < 8; ++kt) {
    const int k0 = kt * 32;
#pragma unroll
    for (int it = 0; it < 2; ++it) {
      const int task = it * 256 + tid;
      const int row = task >> 2, c = task & 3;
      u16x8 va = *(const u16x8*)(Obuf + (rb * 128 + row) * 256 + k0 + c * 8);
      *(u16x8*)(la + row * 32 + ((c ^ (row & 3)) << 3)) = va;
      u16x8 vb = *(const u16x8*)(wproj + (cb * 128 + row) * 256 + k0 + c * 8);
      *(u16x8*)(lb + row * 32 + ((c ^ (row & 3)) << 3)) = vb;
    }
    __syncthreads();
    bf16x8 a[4];
#pragma unroll
    for (int af = 0; af < 4; ++af) {
      const int rr = wr * 64 + af * 16 + l16;
      a[af] = lds8(la + rr * 32 + ((lg ^ (rr & 3)) << 3));
    }
#pragma unroll
    for (int cf = 0; cf < 4; ++cf) {
      const int ccc = wc * 64 + cf * 16 + l16;
      bf16x8 bfr = lds8(lb + ccc * 32 + ((lg ^ (ccc & 3)) << 3));
#pragma unroll
      for (int af = 0; af < 4; ++af) acc[af][cf] = mfma16(a[af], bfr, acc[af][cf]);
    }
    __syncthreads();
  }
#pragma unroll
  for (int cf = 0; cf < 4; ++cf) {
    const int col = cb * 128 + wc * 64 + cf * 16 + l16;
    const float pb = proj_b[col];
#pragma unroll
    for (int af = 0; af < 4; ++af)
#pragma unroll
      for (int r = 0; r < 4; ++r) {
        const int row = rb * 128 + wr * 64 + af * 16 + lg * 4 + r;
        out[row * 256 + col] = acc[af][cf][r] + pb;
      }
  }
}

extern "C" void kernel_launch(void* const* d_in, const int* in_sizes, int n_in,
                              void* d_out, int out_size, void* d_ws, size_t ws_size,
                              hipStream_t stream) {
  (void)in_sizes; (void)n_in; (void)out_size; (void)ws_size;
  const float* x = (const float*)d_in[0];
  const float* mask = (const float*)d_in[1];
  const float* qkv_w = (const float*)d_in[2];
  const float* q_bias = (const float*)d_in[3];
  const float* v_bias = (const float*)d_in[4];
  const float* logit_scale = (const float*)d_in[5];
  const float* cpb_w1 = (const float*)d_in[6];
  const float* cpb_b1 = (const float*)d_in[7];
  const float* cpb_w2 = (const float*)d_in[8];
  const float* proj_w = (const float*)d_in[9];
  const float* proj_b = (const float*)d_in[10];
  float* out = (float*)d_out;
  char* ws = (char*)d_ws;

  // workspace layout (~102.3 MB)
  unsigned short* xbb = (unsigned short*)(ws + 0);            // 33,554,432 (half batch)
  unsigned short* Obuf = (unsigned short*)(ws + 33554432);    // 67,108,864
  unsigned short* rpbn = (unsigned short*)(ws + 100663296);   // 1,048,576
  float* bt = (float*)(ws + 101711872);                       // 30,752
  unsigned short* wqkv = (unsigned short*)(ws + 101742624);   // 393,216
  unsigned short* wproj = (unsigned short*)(ws + 102135840);  // 131,072

  k_cvt_w<<<dim3(1024), dim3(256), 0, stream>>>(qkv_w, proj_w, wqkv, wproj);
  k_cpb<<<dim3(961), dim3(64), 0, stream>>>(cpb_w1, cpb_b1, cpb_w2, bt);
  k_rpb<<<dim3(2048), dim3(256), 0, stream>>>(bt, rpbn);

  k_cvt_x<<<dim3(8192), dim3(256), 0, stream>>>(x, xbb);
  k_attn<<<dim3(2048), dim3(1024), 0, stream>>>(xbb, q_bias, v_bias, logit_scale,
                                                wqkv, rpbn, mask, Obuf, 0);
  k_cvt_x<<<dim3(8192), dim3(256), 0, stream>>>(x + 16777216, xbb);
  k_attn<<<dim3(2048), dim3(1024), 0, stream>>>(xbb, q_bias, v_bias, logit_scale,
                                                wqkv, rpbn, mask, Obuf, 256);

  k_proj<<<dim3(2048), dim3(256), 0, stream>>>(Obuf, wproj, proj_b, out);
}

// Round 8
// 407.945 us; speedup vs baseline: 1.8271x; 1.0162x over previous
//
#include <hip/hip_runtime.h>
#include <hip/hip_bf16.h>
#include <hip/hip_fp16.h>

// SwinV2 window attention, MI355X/gfx950.
// Pipeline: cvt_w, cpb, rpb (1MB natural-layout bias, log2e-folded),
//           2x [cvt_x(half) -> attn(half)], proj.
// attn: 1024 thr / 16 waves, 2 blocks/CU (LDS 77824, VGPR<=64).
// Phase B: swapped QK^T + online softmax; R8 change: P (and q-hat) fed to
// MFMA via IN-REGISTER exchange — k-slot permutation pi(lg) makes the
// m<->lane transpose a pure lane^16 shuffle (4 cvt_pk + 4 shfl_xor), so the
// per-chunk LDS staging round-trip (2 ds_write + lgkmcnt(0) + ds_read) and
// the lq buffer are deleted; chunk loop unrolled 2x; exact defer-rescale.

#define LOG100F 4.605170185988091f
#define LOG2EF 1.4426950408889634f

typedef __attribute__((ext_vector_type(8))) __bf16 bf16x8;
typedef __attribute__((ext_vector_type(4))) float f32x4;
typedef __attribute__((ext_vector_type(8))) unsigned short u16x8;
typedef __attribute__((ext_vector_type(4))) unsigned short u16x4;
typedef __attribute__((ext_vector_type(4))) unsigned int u32x4;

__device__ __forceinline__ unsigned short f2bfu(float f) {
  __hip_bfloat16 b = __float2bfloat16(f);
  return __builtin_bit_cast(unsigned short, b);
}
__device__ __forceinline__ unsigned short f2h(float f) {
  __half hv = __float2half(f);
  return __builtin_bit_cast(unsigned short, hv);
}
__device__ __forceinline__ float h2f(unsigned short b) {
  return __half2float(__builtin_bit_cast(__half, b));
}
__device__ __forceinline__ bf16x8 lds8(const unsigned short* p) {
  u16x8 v = *(const u16x8*)p;
  return __builtin_bit_cast(bf16x8, v);
}
__device__ __forceinline__ f32x4 mfma16(bf16x8 a, bf16x8 b, f32x4 c) {
  return __builtin_amdgcn_mfma_f32_16x16x32_bf16(a, b, c, 0, 0, 0);
}
__device__ __forceinline__ float fexp2(float x) {
#if __has_builtin(__builtin_amdgcn_exp2f)
  return __builtin_amdgcn_exp2f(x);
#else
  return exp2f(x);
#endif
}
// pack two f32 -> one u32 of 2 bf16 (lo = a, hi = b), RNE
__device__ __forceinline__ unsigned int cvtpk(float a, float b) {
  unsigned int r;
  asm("v_cvt_pk_bf16_f32 %0, %1, %2" : "=v"(r) : "v"(a), "v"(b));
  return r;
}
// 16B-chunk XOR swizzle for [R][32]-u16 tiles: <=2-way on ds_read_b128
__device__ __forceinline__ int swc(int row, int kchunk) {
  return (kchunk ^ (row & 3) ^ ((row >> 2) & 3)) & 3;
}
__device__ __forceinline__ void gload_lds16(const void* g, void* l) {
  __builtin_amdgcn_global_load_lds(
      (const __attribute__((address_space(1))) void*)g,
      (__attribute__((address_space(3))) void*)l, 16, 0, 0);
}

// ---------------- weights -> bf16 ----------------
__global__ void k_cvt_w(const float* __restrict__ qkv_w, const float* __restrict__ proj_w,
                        unsigned short* __restrict__ wqkv, unsigned short* __restrict__ wproj) {
  const int t = blockIdx.x * 256 + threadIdx.x;
  if (t < 768 * 256) {
    wqkv[t] = f2bfu(qkv_w[t]);
  } else {
    const int t2 = t - 768 * 256;
    wproj[t2] = f2bfu(proj_w[t2]);
  }
}

// ---------------- x -> bf16 (half batch per call) ----------------
__global__ void k_cvt_x(const float* __restrict__ x, unsigned short* __restrict__ xb) {
  const int t = blockIdx.x * 256 + threadIdx.x;
  const float4 a = *(const float4*)(x + (size_t)t * 8);
  const float4 c = *(const float4*)(x + (size_t)t * 8 + 4);
  u16x8 ov;
  ov[0] = f2bfu(a.x); ov[1] = f2bfu(a.y); ov[2] = f2bfu(a.z); ov[3] = f2bfu(a.w);
  ov[4] = f2bfu(c.x); ov[5] = f2bfu(c.y); ov[6] = f2bfu(c.z); ov[7] = f2bfu(c.w);
  *(u16x8*)(xb + (size_t)t * 8) = ov;
}

// ---------------- CPB MLP -> bias_table[961][8] ----------------
__global__ void k_cpb(const float* __restrict__ w1, const float* __restrict__ b1,
                      const float* __restrict__ w2, float* __restrict__ bt) {
  const int row = blockIdx.x;
  const int lane = threadIdx.x;
  const int i = row / 31, j = row % 31;
  float x0 = (i - 15) * (1.0f / 15.0f);
  float x1 = (j - 15) * (1.0f / 15.0f);
  float v0 = log2f(fmaf(8.0f, fabsf(x0), 1.0f)) * (1.0f / 3.0f); v0 = x0 < 0.0f ? -v0 : v0;
  float v1 = log2f(fmaf(8.0f, fabsf(x1), 1.0f)) * (1.0f / 3.0f); v1 = x1 < 0.0f ? -v1 : v1;
  float a[8] = {0.f, 0.f, 0.f, 0.f, 0.f, 0.f, 0.f, 0.f};
  for (int jj = lane; jj < 512; jj += 64) {
    float hv = fmaf(w1[2 * jj], v0, fmaf(w1[2 * jj + 1], v1, b1[jj]));
    hv = fmaxf(hv, 0.0f);
#pragma unroll
    for (int hh = 0; hh < 8; ++hh) a[hh] = fmaf(hv, w2[hh * 512 + jj], a[hh]);
  }
#pragma unroll
  for (int hh = 0; hh < 8; ++hh) {
#pragma unroll
    for (int mm = 1; mm < 64; mm <<= 1) a[hh] += __shfl_xor(a[hh], mm);
  }
  float outv = a[0];
#pragma unroll
  for (int hh = 1; hh < 8; ++hh)
    if (lane == hh) outv = a[hh];
  if (lane < 8) bt[row * 8 + lane] = outv;
}

// ------- rpbn[h][n][m] = fp16(log2e * 16*sigmoid(bt[idx(n,m)][h])) -------
__global__ void k_rpb(const float* __restrict__ bt, unsigned short* __restrict__ rpbn) {
  const int t = blockIdx.x * 256 + threadIdx.x;  // 2048 blocks -> 524288
  const int m = t & 255, n = (t >> 8) & 255, h = t >> 16;
  const int ih = n >> 4, iw = n & 15, jh = m >> 4, jw = m & 15;
  const int idx = (ih - jh + 15) * 31 + (iw - jw + 15);
  const float bv = bt[idx * 8 + h];
  rpbn[t] = f2h(LOG2EF * 16.0f / (1.0f + __expf(-bv)));
}

// ---------------- fused qkv + cosine attention, per (b,h) ----------------
__global__ __launch_bounds__(1024, 8) void k_attn(
    const unsigned short* __restrict__ xb, const float* __restrict__ q_bias,
    const float* __restrict__ v_bias, const float* __restrict__ logit_scale,
    const unsigned short* __restrict__ wqkv, const unsigned short* __restrict__ rpbn,
    const float* __restrict__ mask, unsigned short* __restrict__ Obuf, int b0) {
  // 77,824 B total -> 2 blocks/CU.
  __shared__ unsigned short lx[2][8192];  // x slice [256 tok][32 k], dbuf (phase A only)
  __shared__ unsigned short lw[2][3072];  // W_h slice [96][32], dbuf
  __shared__ unsigned short lk[8192];     // k-hat [256 tok][32 d]
  __shared__ unsigned short lv[8192];     // v^T  [32 d][256 tok]

  // XCD-aware map: bid = g*64 + h*8 + x (x = XCD = bid%8); bl = g*8 + x.
  const int bid = blockIdx.x;
  const int xcd = bid & 7, h = (bid >> 3) & 7, g = bid >> 6;
  const int bl = g * 8 + xcd;
  const int b = b0 + bl;
  const int w = b & 63;
  const int tid = threadIdx.x;
  const int lane = tid & 63, wid = tid >> 6;
  const int l16 = lane & 15, lg = lane >> 4;
  // k-slot permutation: slot lg covers d/token-range pig*8..+7 (bit-swap of lg)
  const int pig = ((lg & 1) << 1) | (lg >> 1);

  // ---- phase A: [96 wcols x 256 tok] = W_h . x^T, K=256 in 8 slices ----
  const int srow = wid * 16 + (lane >> 2);
  const int pc = lane & 3;
  const int xlc = (pc ^ (srow & 3) ^ ((srow >> 2) & 3)) & 3;
  const unsigned short* xsrc0 = xb + (((bl << 8) + srow) << 8) + (xlc << 3);
  const unsigned short* wsrc0 =
      wqkv + ((((srow >> 5) << 8) + h * 32 + (srow & 31)) << 8) + (xlc << 3);

  f32x4 acc[6];
#pragma unroll
  for (int i = 0; i < 6; ++i) acc[i] = (f32x4){0.f, 0.f, 0.f, 0.f};

  gload_lds16(xsrc0, &lx[0][wid * 512]);
  if (wid < 6) gload_lds16(wsrc0, &lw[0][wid * 512]);
  __syncthreads();

  for (int kt = 0; kt < 8; ++kt) {
    const int cur = kt & 1;
    if (kt < 7) {
      const int k0 = (kt + 1) << 5;
      gload_lds16(xsrc0 + k0, &lx[cur ^ 1][wid * 512]);
      if (wid < 6) gload_lds16(wsrc0 + k0, &lw[cur ^ 1][wid * 512]);
    }
    const unsigned short* lxb = lx[cur];
    const unsigned short* lwb = lw[cur];
    const int n = wid * 16 + l16;
    const bf16x8 ax = lds8(lxb + n * 32 + (swc(n, lg) << 3));
#pragma unroll
    for (int mf = 0; mf < 6; ++mf) {
      const int m = mf * 16 + l16;
      const bf16x8 aw = lds8(lwb + m * 32 + (swc(m, lg) << 3));
      acc[mf] = mfma16(aw, ax, acc[mf]);
    }
    __syncthreads();
  }

  // ---- epilogue: lane owns token tok = wid*16+l16; d = mf*16+lg*4+r ----
  const float sl = __expf(fminf(logit_scale[h], LOG100F)) * LOG2EF;
  const int tok = wid * 16 + l16;
  const float4 qb0 = *(const float4*)(q_bias + h * 32 + lg * 4);
  const float4 qb1 = *(const float4*)(q_bias + h * 32 + 16 + lg * 4);

  bf16x8 aq;  // B-frag for QK: k-slot lg <-> d = pig*8..+7, col q = l16
  {
    float q0[4], q1[4];
    float sq = 0.f, sk = 0.f;
#pragma unroll
    for (int r = 0; r < 4; ++r) {
      q0[r] = acc[0][r] + ((const float*)&qb0)[r];
      q1[r] = acc[1][r] + ((const float*)&qb1)[r];
      sq += q0[r] * q0[r] + q1[r] * q1[r];
      sk += acc[2][r] * acc[2][r] + acc[3][r] * acc[3][r];
    }
    sq += __shfl_xor(sq, 16); sq += __shfl_xor(sq, 32);
    sk += __shfl_xor(sk, 16); sk += __shfl_xor(sk, 32);
    const float rq = sl / fmaxf(sqrtf(sq), 1e-12f);
    const float rk = 1.f / fmaxf(sqrtf(sk), 1e-12f);
    // q-hat: pack + lane^16 exchange -> A-frag in registers (no lq buffer)
    const unsigned int cq00 = cvtpk(q0[0] * rq, q0[1] * rq);
    const unsigned int cq01 = cvtpk(q0[2] * rq, q0[3] * rq);
    const unsigned int cq10 = cvtpk(q1[0] * rq, q1[1] * rq);
    const unsigned int cq11 = cvtpk(q1[2] * rq, q1[3] * rq);
    const unsigned int xq00 = (unsigned)__shfl_xor((int)cq00, 16);
    const unsigned int xq01 = (unsigned)__shfl_xor((int)cq01, 16);
    const unsigned int xq10 = (unsigned)__shfl_xor((int)cq10, 16);
    const unsigned int xq11 = (unsigned)__shfl_xor((int)cq11, 16);
    u32x4 av;
    const bool odd = (lg & 1) != 0;
    av[0] = odd ? xq10 : cq00;
    av[1] = odd ? xq11 : cq01;
    av[2] = odd ? cq10 : xq00;
    av[3] = odd ? cq11 : xq01;
    aq = __builtin_bit_cast(bf16x8, av);
    // k-hat -> LDS (read by all waves)
    const int off0 = (lg & 1) * 4;
    u16x4 c, c2;
#pragma unroll
    for (int r = 0; r < 4; ++r) { c[r] = f2bfu(acc[2][r] * rk); c2[r] = f2bfu(acc[3][r] * rk); }
    const int kc0 = lg >> 1;
    *(u16x4*)(lk + tok * 32 + (swc(tok, kc0) << 3) + off0) = c;
    const int kc1 = 2 + (lg >> 1);
    *(u16x4*)(lk + tok * 32 + (swc(tok, kc1) << 3) + off0) = c2;
  }
#pragma unroll
  for (int mf = 0; mf < 2; ++mf) {
    const float4 vb = *(const float4*)(v_bias + h * 32 + mf * 16 + lg * 4);
#pragma unroll
    for (int r = 0; r < 4; ++r) {
      const int dd = mf * 16 + lg * 4 + r;
      const float vv = acc[4 + mf][r] + ((const float*)&vb)[r];
      lv[dd * 256 + ((((tok >> 3) ^ dd) & 31) << 3) + (tok & 7)] = f2bfu(vv);
    }
  }
  __syncthreads();

  // ---- phase B: swapped QK^T + online softmax + PV, in-register P ----
  // lane owns stats for q-row l16 (partial over its lg's m); o rows = lg*4+r.
  const int q = wid * 16 + l16;
  const unsigned short* rbp = rpbn + (h << 16) + (q << 8) + lg * 4;
  const float* mbp = mask + (w << 16) + (q << 8) + lg * 4;

  float mx = -3.0e38f, sm = 0.f;
  f32x4 o0 = (f32x4){0.f, 0.f, 0.f, 0.f}, o1 = (f32x4){0.f, 0.f, 0.f, 0.f};

#pragma unroll 2
  for (int cc = 0; cc < 8; ++cc) {
    // QK^T: s[r] = S[m = cc*32 + q8*16 + lg*4+r][q=l16]; k-chunks via pig
    const int m0 = cc * 32 + l16;
    const bf16x8 bk0 = lds8(lk + m0 * 32 + (swc(m0, pig) << 3));
    f32x4 s0 = mfma16(bk0, aq, (f32x4){0.f, 0.f, 0.f, 0.f});
    const int m1 = m0 + 16;
    const bf16x8 bk1 = lds8(lk + m1 * 32 + (swc(m1, pig) << 3));
    f32x4 s1 = mfma16(bk1, aq, (f32x4){0.f, 0.f, 0.f, 0.f});
    // bias (natural layout; m = cc*32 + q8*16 + lg*4 + r)
    {
      const u16x4 rv0 = *(const u16x4*)(rbp + cc * 32);
      const float4 mv0 = *(const float4*)(mbp + cc * 32);
      s0[0] = fmaf(mv0.x, LOG2EF, s0[0] + h2f(rv0[0]));
      s0[1] = fmaf(mv0.y, LOG2EF, s0[1] + h2f(rv0[1]));
      s0[2] = fmaf(mv0.z, LOG2EF, s0[2] + h2f(rv0[2]));
      s0[3] = fmaf(mv0.w, LOG2EF, s0[3] + h2f(rv0[3]));
      const u16x4 rv1 = *(const u16x4*)(rbp + cc * 32 + 16);
      const float4 mv1 = *(const float4*)(mbp + cc * 32 + 16);
      s1[0] = fmaf(mv1.x, LOG2EF, s1[0] + h2f(rv1[0]));
      s1[1] = fmaf(mv1.y, LOG2EF, s1[1] + h2f(rv1[1]));
      s1[2] = fmaf(mv1.z, LOG2EF, s1[2] + h2f(rv1[2]));
      s1[3] = fmaf(mv1.w, LOG2EF, s1[3] + h2f(rv1[3]));
    }
    // chunk max over 32 m (8 in-lane + lg reduce); uniform across lg
    float cmax = fmaxf(fmaxf(fmaxf(s0[0], s0[1]), fmaxf(s0[2], s0[3])),
                       fmaxf(fmaxf(s1[0], s1[1]), fmaxf(s1[2], s1[3])));
    cmax = fmaxf(cmax, __shfl_xor(cmax, 16));
    cmax = fmaxf(cmax, __shfl_xor(cmax, 32));
    // exact defer: rescale only when the running max actually grows
    if (!__all(cmax <= mx)) {
      const float mnew = fmaxf(mx, cmax);
      const float factor = fexp2(mx - mnew);
      sm *= factor;
#pragma unroll
      for (int r = 0; r < 4; ++r) {
        const float of = __shfl(factor, lg * 4 + r);
        o0[r] *= of;
        o1[r] *= of;
      }
      mx = mnew;
    }
    // p = exp2(s - mx); partial denominator; pack to bf16 pairs
    float p00, p01, p02, p03, p10, p11, p12, p13;
    p00 = fexp2(s0[0] - mx); p01 = fexp2(s0[1] - mx);
    p02 = fexp2(s0[2] - mx); p03 = fexp2(s0[3] - mx);
    p10 = fexp2(s1[0] - mx); p11 = fexp2(s1[1] - mx);
    p12 = fexp2(s1[2] - mx); p13 = fexp2(s1[3] - mx);
    sm += ((p00 + p01) + (p02 + p03)) + ((p10 + p11) + (p12 + p13));
    const unsigned int c00 = cvtpk(p00, p01), c01 = cvtpk(p02, p03);
    const unsigned int c10 = cvtpk(p10, p11), c11 = cvtpk(p12, p13);
    // lane^16 exchange -> PV A-frag (k-slot lg <-> tokens cc*32 + pig*8..+7)
    const unsigned int x00 = (unsigned)__shfl_xor((int)c00, 16);
    const unsigned int x01 = (unsigned)__shfl_xor((int)c01, 16);
    const unsigned int x10 = (unsigned)__shfl_xor((int)c10, 16);
    const unsigned int x11 = (unsigned)__shfl_xor((int)c11, 16);
    u32x4 pw;
    const bool odd = (lg & 1) != 0;
    pw[0] = odd ? x10 : c00;
    pw[1] = odd ? x11 : c01;
    pw[2] = odd ? c10 : x00;
    pw[3] = odd ? c11 : x01;
    const bf16x8 pa = __builtin_bit_cast(bf16x8, pw);
    const int d0 = l16;
    const bf16x8 bv0 = lds8(lv + d0 * 256 + ((((cc * 4 + pig) ^ d0) & 31) << 3));
    o0 = mfma16(pa, bv0, o0);
    const int d1 = 16 + l16;
    const bf16x8 bv1 = lds8(lv + d1 * 256 + ((((cc * 4 + pig) ^ d1) & 31) << 3));
    o1 = mfma16(pa, bv1, o1);
  }
  // total denominator = sum of the 4 lg-group partials (factor history is
  // uniform across lg, so partials add linearly).
  sm += __shfl_xor(sm, 16);
  sm += __shfl_xor(sm, 32);
  // O rows = q_local = lg*4+r; fetch that row's normalizer from lane lg*4+r
  const float inv = 1.f / sm;
#pragma unroll
  for (int r = 0; r < 4; ++r) {
    const float iv = __shfl(inv, lg * 4 + r);
    const int row = (b * 256 + wid * 16 + lg * 4 + r) << 8;
    Obuf[row + h * 32 + l16] = f2bfu(o0[r] * iv);
    Obuf[row + h * 32 + 16 + l16] = f2bfu(o1[r] * iv);
  }
}

// ---------------- out = O @ proj_w^T + proj_b (fp32) ----------------
__global__ __launch_bounds__(256, 2) void k_proj(
    const unsigned short* __restrict__ Obuf, const unsigned short* __restrict__ wproj,
    const float* __restrict__ proj_b, float* __restrict__ out) {
  __shared__ unsigned short la[128 * 32];
  __shared__ unsigned short lb[128 * 32];
  const int rb = blockIdx.x >> 1, cb = blockIdx.x & 1;
  const int tid = threadIdx.x, lane = tid & 63, wid = tid >> 6;
  const int wr = wid >> 1, wc = wid & 1;
  const int l16 = lane & 15, lg = lane >> 4;
  f32x4 acc[4][4];
#pragma unroll
  for (int i = 0; i < 4; ++i)
#pragma unroll
    for (int j = 0; j < 4; ++j) acc[i][j] = (f32x4){0.f, 0.f, 0.f, 0.f};
  for (int kt = 0; kt < 8; ++kt) {
    const int k0 = kt * 32;
#pragma unroll
    for (int it = 0; it < 2; ++it) {
      const int task = it * 256 + tid;
      const int row = task >> 2, c = task & 3;
      u16x8 va = *(const u16x8*)(Obuf + (rb * 128 + row) * 256 + k0 + c * 8);
      *(u16x8*)(la + row * 32 + ((c ^ (row & 3)) << 3)) = va;
      u16x8 vb = *(const u16x8*)(wproj + (cb * 128 + row) * 256 + k0 + c * 8);
      *(u16x8*)(lb + row * 32 + ((c ^ (row & 3)) << 3)) = vb;
    }
    __syncthreads();
    bf16x8 a[4];
#pragma unroll
    for (int af = 0; af < 4; ++af) {
      const int rr = wr * 64 + af * 16 + l16;
      a[af] = lds8(la + rr * 32 + ((lg ^ (rr & 3)) << 3));
    }
#pragma unroll
    for (int cf = 0; cf < 4; ++cf) {
      const int ccc = wc * 64 + cf * 16 + l16;
      bf16x8 bfr = lds8(lb + ccc * 32 + ((lg ^ (ccc & 3)) << 3));
#pragma unroll
      for (int af = 0; af < 4; ++af) acc[af][cf] = mfma16(a[af], bfr, acc[af][cf]);
    }
    __syncthreads();
  }
#pragma unroll
  for (int cf = 0; cf < 4; ++cf) {
    const int col = cb * 128 + wc * 64 + cf * 16 + l16;
    const float pb = proj_b[col];
#pragma unroll
    for (int af = 0; af < 4; ++af)
#pragma unroll
      for (int r = 0; r < 4; ++r) {
        const int row = rb * 128 + wr * 64 + af * 16 + lg * 4 + r;
        out[row * 256 + col] = acc[af][cf][r] + pb;
      }
  }
}

extern "C" void kernel_launch(void* const* d_in, const int* in_sizes, int n_in,
                              void* d_out, int out_size, void* d_ws, size_t ws_size,
                              hipStream_t stream) {
  (void)in_sizes; (void)n_in; (void)out_size; (void)ws_size;
  const float* x = (const float*)d_in[0];
  const float* mask = (const float*)d_in[1];
  const float* qkv_w = (const float*)d_in[2];
  const float* q_bias = (const float*)d_in[3];
  const float* v_bias = (const float*)d_in[4];
  const float* logit_scale = (const float*)d_in[5];
  const float* cpb_w1 = (const float*)d_in[6];
  const float* cpb_b1 = (const float*)d_in[7];
  const float* cpb_w2 = (const float*)d_in[8];
  const float* proj_w = (const float*)d_in[9];
  const float* proj_b = (const float*)d_in[10];
  float* out = (float*)d_out;
  char* ws = (char*)d_ws;

  // workspace layout (~102.3 MB)
  unsigned short* xbb = (unsigned short*)(ws + 0);            // 33,554,432 (half batch)
  unsigned short* Obuf = (unsigned short*)(ws + 33554432);    // 67,108,864
  unsigned short* rpbn = (unsigned short*)(ws + 100663296);   // 1,048,576
  float* bt = (float*)(ws + 101711872);                       // 30,752
  unsigned short* wqkv = (unsigned short*)(ws + 101742624);   // 393,216
  unsigned short* wproj = (unsigned short*)(ws + 102135840);  // 131,072

  k_cvt_w<<<dim3(1024), dim3(256), 0, stream>>>(qkv_w, proj_w, wqkv, wproj);
  k_cpb<<<dim3(961), dim3(64), 0, stream>>>(cpb_w1, cpb_b1, cpb_w2, bt);
  k_rpb<<<dim3(2048), dim3(256), 0, stream>>>(bt, rpbn);

  k_cvt_x<<<dim3(8192), dim3(256), 0, stream>>>(x, xbb);
  k_attn<<<dim3(2048), dim3(1024), 0, stream>>>(xbb, q_bias, v_bias, logit_scale,
                                                wqkv, rpbn, mask, Obuf, 0);
  k_cvt_x<<<dim3(8192), dim3(256), 0, stream>>>(x + 16777216, xbb);
  k_attn<<<dim3(2048), dim3(1024), 0, stream>>>(xbb, q_bias, v_bias, logit_scale,
                                                wqkv, rpbn, mask, Obuf, 256);

  k_proj<<<dim3(2048), dim3(256), 0, stream>>>(Obuf, wproj, proj_b, out);
}